// Round 8
// baseline (302.535 us; speedup 1.0000x reference)
//
#include <hip/hip_runtime.h>

// int4-dequant GEMM: y[m,n] = sum_k x[m,k] * scale[n, k/128] * (q[n,k] - 8)
// x: (512,4096) f32 | weight_packed: (11008,2048) int32 (2 nibbles in LOW byte) |
// scales: (11008,32) f32 | out: (512,11008) f32
//
// R15: dataflow restructure. Post-mortem R7-R14: every barrier+LDS-staged
// variant pins at 101-156us (MfmaUtil 12-18) regardless of occupancy or
// schedule -- the per-iter serial {stage+dequant+2 barriers} dominates.
// Also: weight_packed is int32 per 2 nibbles = 90 MB raw -- every round paid
// 4x inflated weight bytes.
// Fix:
//  1) repack_w (one-time, memory-bound): 90 MB int32 -> 45 MB u8 nibble-values
//     in MFMA-FRAGMENT order: chunk c=(stripe*256+k16)*64+lane holds lane's 8
//     weights (n=stripe*32+(lane&31), k=k16*16+(lane>>5)*8..+8) as 8 bytes.
//  2) dq_gemm: NO LDS, NO barriers. Both operands are coalesced per-lane
//     fragment streams (A: dwordx4 bf16 from xw; B: dwordx2 u8 from wq,
//     dequant in-reg ~20 VALU/frag via cvt_f32_ubyte+fma+pack, overlapped
//     with MFMA). 2-step register double-buffer (aA/aB, qA/qB, static idx),
//     scales prefetched one group ahead. Waves drift freely (pure ILP+TLP).
// Geometry: BM=64 BN=128, 2-wave blocks (wave-tile 64x64, acc[2][2]=64 AGPR),
// grid 688 = 8 XCDs x 86; G=(bx&7)*86+(bx>>3), m_idx=G&7 inner -> one n-panel's
// 8 m-blocks on one XCD (256 KB compact B panel L2-reused 8x); A frags shared
// by both waves of a block (L1). launch_bounds(128,2): 256-reg budget, no spill.
// Verified pieces: fragment-layout cvt_x (R10+), dequant math (R7+), C/D map
// (col=lane&31, row=(r&3)+8*(r>>2)+4*(lane>>5)).
// Tripwires: dq_gemm WRITE_SIZE must be exactly 22016 KB; LDS_Block_Size 0.

typedef __attribute__((ext_vector_type(8)))  short short8;   // 32x32x16 A/B frag
typedef __attribute__((ext_vector_type(16))) float f32x16;   // 32x32x16 C/D frag
typedef __attribute__((ext_vector_type(4)))  float f32x4;
typedef __attribute__((ext_vector_type(4)))  int   i32x4;
typedef __attribute__((ext_vector_type(2)))  int   i32x2;

#define M_DIM 512
#define N_DIM 11008
#define K_DIM 4096
#define BM 64
#define BN 128
#define THREADS 256        // cvt_x / repack_w
#define GTHREADS 128       // dq_gemm: 2 waves
#define NTILE_M (M_DIM / BM)          // 8
#define NTILE_N (N_DIM / BN)          // 86
#define NTILES  (NTILE_M * NTILE_N)   // 688 = 8 * 86
#define KC      (K_DIM / 16)          // 256 k16-steps
#define NSTRIPE (N_DIM / 32)          // 344

#if defined(__has_builtin)
#  if __has_builtin(__builtin_amdgcn_cvt_pk_bf16_f32)
#    define HAVE_PK_BF16 1
#  endif
#endif
#ifndef HAVE_PK_BF16
#  define HAVE_PK_BF16 0
#endif

__device__ __forceinline__ unsigned int fbits(float f) {
    union { float f; unsigned int u; } c; c.f = f; return c.u;
}
__device__ __forceinline__ int pack2bf(float lo, float hi) {  // [hi|lo] bf16, RNE
#if HAVE_PK_BF16
    typedef __attribute__((ext_vector_type(2))) __bf16 bf16x2;
    bf16x2 p = __builtin_amdgcn_cvt_pk_bf16_f32(lo, hi);
    int r; __builtin_memcpy(&r, &p, 4);
    return r;
#else
    unsigned int ul = fbits(lo), uh = fbits(hi);
    unsigned int l = (ul + 0x7FFFu + ((ul >> 16) & 1u)) >> 16;
    unsigned int h = (uh + 0x7FFFu + ((uh >> 16) & 1u)) & 0xFFFF0000u;
    return (int)(h | l);
#endif
}

// ---- x f32 -> bf16 fragment-layout workspace (verified R10..R14) ----
// chunk c: lane=c&63, k16=(c>>6)&255, mb=c>>14; m=mb*32+(lane&31), k=k16*16+(lane>>5)*8
__global__ __launch_bounds__(THREADS)
void cvt_x(const float* __restrict__ x, unsigned short* __restrict__ xw)
{
    int c    = blockIdx.x * THREADS + threadIdx.x;
    int lane = c & 63;
    int kb   = (c >> 6) & (KC - 1);
    int mb   = c >> 14;
    int m    = mb * 32 + (lane & 31);
    int k    = kb * 16 + (lane >> 5) * 8;

    const float* src = x + (size_t)m * K_DIM + k;
    f32x4 v0 = *(const f32x4*)(src);
    f32x4 v1 = *(const f32x4*)(src + 4);
    i32x4 p;
    p[0] = pack2bf(v0[0], v0[1]);
    p[1] = pack2bf(v0[2], v0[3]);
    p[2] = pack2bf(v1[0], v1[1]);
    p[3] = pack2bf(v1[2], v1[3]);
    *(i32x4*)(xw + (size_t)c * 8) = p;
}

// ---- weights int32-nibbles -> u8 nibble-values in fragment order ----
// output chunk d (8 bytes): lane=d&63, k16=(d>>6)&255, stripe=d>>14.
// row n = stripe*32 + (lane&31); weights k = k16*16 + (lane>>5)*8 + e, e=0..7.
// int32 j of row holds k=2j (low nib), 2j+1 (high nib) -> j0 = k16*8+(lane>>5)*4.
__global__ __launch_bounds__(THREADS)
void repack_w(const int* __restrict__ wp, unsigned int* __restrict__ wq)
{
    int d      = blockIdx.x * THREADS + threadIdx.x;   // [0, NSTRIPE*KC*64)
    int lane   = d & 63;
    int k16    = (d >> 6) & (KC - 1);
    int stripe = d >> 14;
    int lr = lane & 31, hi = lane >> 5;
    int row = stripe * 32 + lr;
    int j0  = k16 * 8 + hi * 4;

    i32x4 v = *(const i32x4*)(wp + (size_t)row * (K_DIM / 2) + j0);
    unsigned int d0 =  (unsigned int)(v[0] & 15)
                    | ((unsigned int)((v[0] >> 4) & 15) << 8)
                    | ((unsigned int)(v[1] & 15) << 16)
                    | ((unsigned int)((v[1] >> 4) & 15) << 24);
    unsigned int d1 =  (unsigned int)(v[2] & 15)
                    | ((unsigned int)((v[2] >> 4) & 15) << 8)
                    | ((unsigned int)(v[3] & 15) << 16)
                    | ((unsigned int)((v[3] >> 4) & 15) << 24);
    i32x2 o; o[0] = (int)d0; o[1] = (int)d1;
    *(i32x2*)(wq + (size_t)d * 2) = o;
}

// dequant 8 nibble-bytes -> bf16x8 frag: w = q*s - 8s
__device__ __forceinline__ short8 deq8(i32x2 q, float s, float ns8)
{
    unsigned int w0 = (unsigned int)q[0], w1 = (unsigned int)q[1];
    i32x4 r;
    r[0] = pack2bf(fmaf((float)(w0 & 0xFF), s, ns8),
                   fmaf((float)((w0 >> 8) & 0xFF), s, ns8));
    r[1] = pack2bf(fmaf((float)((w0 >> 16) & 0xFF), s, ns8),
                   fmaf((float)(w0 >> 24), s, ns8));
    r[2] = pack2bf(fmaf((float)(w1 & 0xFF), s, ns8),
                   fmaf((float)((w1 >> 8) & 0xFF), s, ns8));
    r[3] = pack2bf(fmaf((float)((w1 >> 16) & 0xFF), s, ns8),
                   fmaf((float)(w1 >> 24), s, ns8));
    short8 out; __builtin_memcpy(&out, &r, 16);
    return out;
}

// fallback dequant from 4 raw int32 (2 nibbles each) — R7 math verbatim
__device__ __forceinline__ short8 deq_raw(i32x4 v, float s, float ns8)
{
    i32x4 r;
    #pragma unroll
    for (int e = 0; e < 4; ++e) {
        int b = v[e];
        r[e] = pack2bf((float)(b & 15) * s + ns8,
                       (float)((b >> 4) & 15) * s + ns8);
    }
    short8 out; __builtin_memcpy(&out, &r, 16);
    return out;
}

// ---- main GEMM: 64x128 tile, 2 waves of 64x64, no LDS, no barriers ----
template<bool PRE>
__global__ __launch_bounds__(GTHREADS, 2)
void dq_gemm(const unsigned short* __restrict__ xw,
             const float* __restrict__ xf,
             const unsigned int* __restrict__ wq,
             const int* __restrict__ wp,
             const float* __restrict__ scales,
             float* __restrict__ out)
{
    const int t  = threadIdx.x;
    const int bx = blockIdx.x;

    // XCD-grouped bijective mapping: one n-panel's 8 m-blocks on one XCD.
    const int G     = (bx & 7) * 86 + (bx >> 3);   // [0,688)
    const int nb    = G >> 3;                      // [0,86)
    const int m_idx = G & 7;                       // [0,8)
    const int m0 = m_idx * BM;
    const int n0 = nb * BN;

    const int wave = t >> 6;
    const int lane = t & 63;
    const int lr = lane & 31;
    const int hi = lane >> 5;
    const int wn = wave * 64;

    // A: fragment chunks of 8 shorts; stripes m0/32 + i
    const short8* xa = (const short8*)xw;
    const int ab0 = ((m0 >> 5) + 0) * (KC * 64) + lane;
    const int ab1 = ((m0 >> 5) + 1) * (KC * 64) + lane;
    // B: fragment chunks of 8 bytes; stripes n0/32 + wave*2 + j
    const i32x2* wb = (const i32x2*)wq;
    const int bb0 = ((n0 >> 5) + wave * 2 + 0) * (KC * 64) + lane;
    const int bb1 = ((n0 >> 5) + wave * 2 + 1) * (KC * 64) + lane;
    // scale rows for this wave's two n-frags (scales: (N, 32) f32)
    const int srow0 = (n0 + wn + lr) * (K_DIM / 128);
    const int srow1 = (n0 + wn + 32 + lr) * (K_DIM / 128);

    f32x16 acc[2][2] = {};

    if constexpr (PRE) {
        short8 aA[2], aB[2];
        i32x2  qA[2], qB[2];

        // prologue: 2-step prefetch
        aA[0] = xa[ab0];      aA[1] = xa[ab1];
        qA[0] = wb[bb0];      qA[1] = wb[bb1];
        aB[0] = xa[ab0 + 64]; aB[1] = xa[ab1 + 64];
        qB[0] = wb[bb0 + 64]; qB[1] = wb[bb1 + 64];

        float sc0 = scales[srow0], sc1 = scales[srow1];
        float nx0 = 0.f, nx1 = 0.f;

        for (int g = 0; g < 32; ++g) {
            if (g < 31) {                       // scale prefetch, 8 steps deep
                nx0 = scales[srow0 + g + 1];
                nx1 = scales[srow1 + g + 1];
            }
            const float s0 = sc0, n80 = sc0 * -8.0f;
            const float s1 = sc1, n81 = sc1 * -8.0f;

            #pragma unroll
            for (int u = 0; u < 4; ++u) {
                const int s = g * 8 + u * 2;
                {   // even step: consume A-buffers, refill for s+2
                    short8 b0 = deq8(qA[0], s0, n80);
                    short8 b1 = deq8(qA[1], s1, n81);
                    acc[0][0] = __builtin_amdgcn_mfma_f32_32x32x16_bf16(aA[0], b0, acc[0][0], 0, 0, 0);
                    acc[1][0] = __builtin_amdgcn_mfma_f32_32x32x16_bf16(aA[1], b0, acc[1][0], 0, 0, 0);
                    acc[0][1] = __builtin_amdgcn_mfma_f32_32x32x16_bf16(aA[0], b1, acc[0][1], 0, 0, 0);
                    acc[1][1] = __builtin_amdgcn_mfma_f32_32x32x16_bf16(aA[1], b1, acc[1][1], 0, 0, 0);
                    if (s + 2 < KC) {
                        aA[0] = xa[ab0 + (s + 2) * 64]; aA[1] = xa[ab1 + (s + 2) * 64];
                        qA[0] = wb[bb0 + (s + 2) * 64]; qA[1] = wb[bb1 + (s + 2) * 64];
                    }
                }
                {   // odd step: consume B-buffers, refill for s+3
                    short8 b0 = deq8(qB[0], s0, n80);
                    short8 b1 = deq8(qB[1], s1, n81);
                    acc[0][0] = __builtin_amdgcn_mfma_f32_32x32x16_bf16(aB[0], b0, acc[0][0], 0, 0, 0);
                    acc[1][0] = __builtin_amdgcn_mfma_f32_32x32x16_bf16(aB[1], b0, acc[1][0], 0, 0, 0);
                    acc[0][1] = __builtin_amdgcn_mfma_f32_32x32x16_bf16(aB[0], b1, acc[0][1], 0, 0, 0);
                    acc[1][1] = __builtin_amdgcn_mfma_f32_32x32x16_bf16(aB[1], b1, acc[1][1], 0, 0, 0);
                    if (s + 3 < KC) {
                        aB[0] = xa[ab0 + (s + 3) * 64]; aB[1] = xa[ab1 + (s + 3) * 64];
                        qB[0] = wb[bb0 + (s + 3) * 64]; qB[1] = wb[bb1 + (s + 3) * 64];
                    }
                }
            }
            sc0 = nx0; sc1 = nx1;
        }
    } else {
        // correctness-only fallback (ws too small): direct reads, no repack
        for (int s = 0; s < KC; ++s) {
            const int g = s >> 3;
            const float s0 = scales[srow0 + g], n80 = s0 * -8.0f;
            const float s1 = scales[srow1 + g], n81 = s1 * -8.0f;
            short8 a[2];
            #pragma unroll
            for (int i = 0; i < 2; ++i) {
                const float* src = xf + (size_t)(m0 + i * 32 + lr) * K_DIM + s * 16 + hi * 8;
                f32x4 v0 = *(const f32x4*)(src);
                f32x4 v1 = *(const f32x4*)(src + 4);
                i32x4 p;
                p[0] = pack2bf(v0[0], v0[1]);
                p[1] = pack2bf(v0[2], v0[3]);
                p[2] = pack2bf(v1[0], v1[1]);
                p[3] = pack2bf(v1[2], v1[3]);
                __builtin_memcpy(&a[i], &p, 16);
            }
            i32x4 v0 = *(const i32x4*)(wp + (size_t)(n0 + wn + lr) * (K_DIM / 2) + s * 8 + hi * 4);
            i32x4 v1 = *(const i32x4*)(wp + (size_t)(n0 + wn + 32 + lr) * (K_DIM / 2) + s * 8 + hi * 4);
            short8 b0 = deq_raw(v0, s0, n80);
            short8 b1 = deq_raw(v1, s1, n81);
            acc[0][0] = __builtin_amdgcn_mfma_f32_32x32x16_bf16(a[0], b0, acc[0][0], 0, 0, 0);
            acc[1][0] = __builtin_amdgcn_mfma_f32_32x32x16_bf16(a[1], b0, acc[1][0], 0, 0, 0);
            acc[0][1] = __builtin_amdgcn_mfma_f32_32x32x16_bf16(a[0], b1, acc[0][1], 0, 0, 0);
            acc[1][1] = __builtin_amdgcn_mfma_f32_32x32x16_bf16(a[1], b1, acc[1][1], 0, 0, 0);
        }
    }

    // direct store: C/D col=lane&31, row=(r&3)+8*(r>>2)+4*(lane>>5)
    const int rbase = hi * 4;
    #pragma unroll
    for (int i = 0; i < 2; ++i) {
        const int mg0 = m0 + i * 32 + rbase;
        #pragma unroll
        for (int j = 0; j < 2; ++j) {
            const int ng = n0 + wn + j * 32 + lr;
            #pragma unroll
            for (int r = 0; r < 16; ++r)
                out[(size_t)(mg0 + (r & 3) + 8 * (r >> 2)) * N_DIM + ng] = acc[i][j][r];
        }
    }
}

extern "C" void kernel_launch(void* const* d_in, const int* in_sizes, int n_in,
                              void* d_out, int out_size, void* d_ws, size_t ws_size,
                              hipStream_t stream) {
    (void)in_sizes; (void)n_in; (void)out_size;
    const float* x      = (const float*)d_in[0];
    const int*   wpck   = (const int*)d_in[1];
    const float* scales = (const float*)d_in[2];
    float*       out    = (float*)d_out;

    const size_t XW_BYTES = (size_t)M_DIM * K_DIM * 2;                 // 4 MB
    const size_t WQ_OFF   = XW_BYTES;
    const size_t WQ_BYTES = (size_t)NSTRIPE * KC * 64 * 8;             // 45.1 MB

    if (ws_size >= WQ_OFF + WQ_BYTES) {
        unsigned short* xw = (unsigned short*)d_ws;
        unsigned int*   wq = (unsigned int*)((char*)d_ws + WQ_OFF);
        cvt_x<<<(M_DIM * K_DIM) / (THREADS * 8), THREADS, 0, stream>>>(x, xw);
        repack_w<<<(NSTRIPE * KC * 64) / THREADS, THREADS, 0, stream>>>(wpck, wq);
        dq_gemm<true><<<NTILES, GTHREADS, 0, stream>>>(xw, x, wq, wpck, scales, out);
    } else {
        dq_gemm<false><<<NTILES, GTHREADS, 0, stream>>>(nullptr, x, nullptr, wpck, scales, out);
    }
}